// Round 4
// baseline (178.403 us; speedup 1.0000x reference)
//
#include <hip/hip_runtime.h>
#include <math.h>

#define NN   4096            // N = V*B
#define BD   2048            // B
#define DF   128             // D
#define INV_T (1.0f/0.07f)
#define SUPP_CAP 32          // max sparsemax support tracked per row (actual ~1-3)

typedef __attribute__((ext_vector_type(8))) short short8v;   // 8 x bf16
typedef __attribute__((ext_vector_type(4))) float float4v;

__device__ inline unsigned short f2bf_rne(float x) {
  unsigned int u = __float_as_uint(x);
  u = (u + 0x7FFFu + ((u >> 16) & 1u)) >> 16;
  return (unsigned short)u;
}
__device__ inline float bf2f(unsigned short h) {
  return __uint_as_float(((unsigned int)h) << 16);
}

// ---------------- Kernel 1: normalize features -> bf16, zero Z ----------------
__global__ void k_prep(const float* __restrict__ feat,
                       unsigned short* __restrict__ fbf,
                       float* __restrict__ Zv) {
  int gid  = blockIdx.x * blockDim.x + threadIdx.x;
  int row  = gid >> 6;                                // one wave per row
  int lane = threadIdx.x & 63;
  const float2* src = (const float2*)(feat + (size_t)row * DF);
  float2 v = src[lane];
  float ss = v.x * v.x + v.y * v.y;
  #pragma unroll
  for (int off = 1; off < 64; off <<= 1) ss += __shfl_xor(ss, off, 64);
  float inv = rsqrtf(ss);
  ushort2 o;
  o.x = f2bf_rne(v.x * inv);
  o.y = f2bf_rne(v.y * inv);
  ((ushort2*)(fbf + (size_t)row * DF))[lane] = o;
  if (gid < NN) Zv[gid] = 0.f;
}

// ---------------- Kernel 2: sparsemax per row + support list ----------------
// One 256-thread block per row; z[16]/thread in VGPRs. Newton iteration
// tau' = (sum_{z>tau} z - 1)/|{z>tau}| from tau0=max-1 (finitely exact).
// Also emits the support set (j, ms) — sparsemax output has ~1-3 nonzeros.
__global__ __launch_bounds__(256) void k_sparsemax(
    const float* __restrict__ attn,
    float* __restrict__ msOut,   // d_out + 1
    int* __restrict__ suppCnt,
    int* __restrict__ suppIdx,
    float* __restrict__ suppVal) {
  __shared__ float redS[4], redC[4];
  __shared__ int scnt;
  int row  = blockIdx.x;
  int tid  = threadIdx.x;
  int lane = tid & 63, wv = tid >> 6;
  const float4* arow = (const float4*)(attn + (size_t)row * NN);
  int rb = row & (BD - 1);
  float z[16];
  #pragma unroll
  for (int u = 0; u < 4; ++u) {
    int q = u * 256 + tid;            // float4 index: perfectly coalesced
    float4 a = arow[q];
    int j = q * 4;
    z[4*u+0] = (((j+0) & (BD-1)) == rb) ? 0.f : a.x * INV_T;
    z[4*u+1] = (((j+1) & (BD-1)) == rb) ? 0.f : a.y * INV_T;
    z[4*u+2] = (((j+2) & (BD-1)) == rb) ? 0.f : a.z * INV_T;
    z[4*u+3] = (((j+3) & (BD-1)) == rb) ? 0.f : a.w * INV_T;
  }
  float m = z[0];
  #pragma unroll
  for (int u = 1; u < 16; ++u) m = fmaxf(m, z[u]);
  #pragma unroll
  for (int off = 1; off < 64; off <<= 1) m = fmaxf(m, __shfl_xor(m, off, 64));
  if (lane == 0) redS[wv] = m;
  __syncthreads();
  m = fmaxf(fmaxf(redS[0], redS[1]), fmaxf(redS[2], redS[3]));

  float tau = m - 1.0f;
  #pragma unroll 1
  for (int it = 0; it < 8; ++it) {
    float S = 0.f, C = 0.f;
    #pragma unroll
    for (int u = 0; u < 16; ++u) {
      bool in = z[u] > tau;
      S += in ? z[u] : 0.f;
      C += in ? 1.f : 0.f;
    }
    #pragma unroll
    for (int off = 1; off < 64; off <<= 1) {
      S += __shfl_xor(S, off, 64);
      C += __shfl_xor(C, off, 64);
    }
    __syncthreads();
    if (lane == 0) { redS[wv] = S; redC[wv] = C; }
    __syncthreads();
    S = (redS[0] + redS[1]) + (redS[2] + redS[3]);
    C = (redC[0] + redC[1]) + (redC[2] + redC[3]);
    tau = (C > 0.f) ? (S - 1.0f) / C : tau;
  }
  if (tid == 0) scnt = 0;
  __syncthreads();

  // store ms and collect support entries (rare -> divergence negligible)
  float* orow = msOut + (size_t)row * NN;
  #pragma unroll
  for (int u = 0; u < 4; ++u) {
    int j = (u * 256 + tid) * 4;
    #pragma unroll
    for (int t = 0; t < 4; ++t) {
      float msv = fmaxf(z[4*u+t] - tau, 0.f);
      orow[j+t] = msv;
      if (msv > 0.f) {
        int slot = atomicAdd(&scnt, 1);
        if (slot < SUPP_CAP) {
          suppIdx[row * SUPP_CAP + slot] = j + t;
          suppVal[row * SUPP_CAP + slot] = msv;
        }
      }
    }
  }
  __syncthreads();
  if (tid == 0) suppCnt[row] = min(scnt, SUPP_CAP);
}

// ---------------- Kernel 3: pure MFMA Gram + Z0 reduction ----------------
// Z0_i = sum_{j != i} exp(sim_ij - 1/T).  F (4096x128 bf16, 1 MB) is
// L2-resident -> no LDS. Block = 4 waves (2x2) -> 128x128 C-tile; wave does
// 64x64 via 4x4 frags of mfma_f32_16x16x32_bf16 over K=128.
__global__ __launch_bounds__(256) void k_gram(
    const unsigned short* __restrict__ fbf, float* __restrict__ Zv) {
  int tid = threadIdx.x;
  int wave = tid >> 6, lane = tid & 63;
  int c = lane & 15, quad = lane >> 4;
  int wi = wave >> 1, wj = wave & 1;
  int i0 = blockIdx.y * 128 + wi * 64;
  int j0 = blockIdx.x * 128 + wj * 64;

  const unsigned short* aBase = fbf + (size_t)(i0 + c) * DF + quad * 8;
  const unsigned short* bBase = fbf + (size_t)(j0 + c) * DF + quad * 8;

  float4v acc[4][4];
  #pragma unroll
  for (int m = 0; m < 4; ++m)
    #pragma unroll
    for (int n = 0; n < 4; ++n) acc[m][n] = (float4v){0.f, 0.f, 0.f, 0.f};

  #pragma unroll
  for (int k0 = 0; k0 < DF; k0 += 32) {
    short8v afr[4], bfr[4];
    #pragma unroll
    for (int m = 0; m < 4; ++m)
      afr[m] = *(const short8v*)(aBase + (size_t)(m * 16) * DF + k0);
    #pragma unroll
    for (int n = 0; n < 4; ++n)
      bfr[n] = *(const short8v*)(bBase + (size_t)(n * 16) * DF + k0);
    #pragma unroll
    for (int m = 0; m < 4; ++m)
      #pragma unroll
      for (int n = 0; n < 4; ++n)
        acc[m][n] = __builtin_amdgcn_mfma_f32_16x16x32_bf16(
            afr[m], bfr[n], acc[m][n], 0, 0, 0);
  }

  // epilogue: Z0_i += exp(sim - 1/T) for j != i   (C/D: col=lane&15, row=quad*4+r)
  #pragma unroll
  for (int m = 0; m < 4; ++m) {
    #pragma unroll
    for (int r = 0; r < 4; ++r) {
      int i = i0 + m * 16 + quad * 4 + r;
      float zsum = 0.f;
      #pragma unroll
      for (int n = 0; n < 4; ++n) {
        int j = j0 + n * 16 + c;
        float e = __expf(acc[m][n][r] * INV_T - INV_T);
        zsum += (i == j) ? 0.f : e;
      }
      zsum += __shfl_xor(zsum, 1, 64);
      zsum += __shfl_xor(zsum, 2, 64);
      zsum += __shfl_xor(zsum, 4, 64);
      zsum += __shfl_xor(zsum, 8, 64);
      if (c == 0) atomicAdd(&Zv[i], zsum);
    }
  }
}

// ---------------- Kernel 3b: sparse correction + numerator ----------------
// One wave per row: numer_i = sim(i, i+B mod N) - 1/T, and
// Z_i -= sum_{e in supp(i)} exp(sim(i,j_e) - 1/T) * ms_e.
__global__ __launch_bounds__(256) void k_corr(
    const unsigned short* __restrict__ fbf,
    const int* __restrict__ suppCnt, const int* __restrict__ suppIdx,
    const float* __restrict__ suppVal,
    float* __restrict__ Zv, float* __restrict__ numer) {
  int tid = threadIdx.x;
  int wave = tid >> 6, lane = tid & 63;
  int row = blockIdx.x * 4 + wave;
  ushort2 a = ((const ushort2*)(fbf + (size_t)row * DF))[lane];
  float ax = bf2f(a.x), ay = bf2f(a.y);

  // positive-pair similarity
  int pos = (row + BD) & (NN - 1);
  ushort2 b = ((const ushort2*)(fbf + (size_t)pos * DF))[lane];
  float d = ax * bf2f(b.x) + ay * bf2f(b.y);
  #pragma unroll
  for (int off = 1; off < 64; off <<= 1) d += __shfl_xor(d, off, 64);
  if (lane == 0) numer[row] = d * INV_T - INV_T;

  int cnt = suppCnt[row];
  float corr = 0.f;
  for (int e = 0; e < cnt; ++e) {
    int j = suppIdx[row * SUPP_CAP + e];
    float v = suppVal[row * SUPP_CAP + e];
    ushort2 g = ((const ushort2*)(fbf + (size_t)j * DF))[lane];
    float s = ax * bf2f(g.x) + ay * bf2f(g.y);
    #pragma unroll
    for (int off = 1; off < 64; off <<= 1) s += __shfl_xor(s, off, 64);
    corr += __expf(s * INV_T - INV_T) * v;
  }
  if (lane == 0 && cnt > 0) atomicAdd(&Zv[row], -corr);
}

// ---------------- Kernel 4: finalize loss (single block) ----------------
__global__ void k_loss(const float* __restrict__ Zv,
                       const float* __restrict__ numer,
                       float* __restrict__ out) {
  float acc = 0.f;
  for (int i = threadIdx.x; i < NN; i += 256)
    acc += numer[i] - logf(Zv[i]);
  #pragma unroll
  for (int off = 1; off < 64; off <<= 1) acc += __shfl_xor(acc, off, 64);
  __shared__ float red[4];
  int wv = threadIdx.x >> 6, lane = threadIdx.x & 63;
  if (lane == 0) red[wv] = acc;
  __syncthreads();
  if (threadIdx.x == 0) {
    float t = (red[0] + red[1]) + (red[2] + red[3]);
    out[0] = -t / (float)NN;
  }
}

extern "C" void kernel_launch(void* const* d_in, const int* in_sizes, int n_in,
                              void* d_out, int out_size, void* d_ws, size_t ws_size,
                              hipStream_t stream) {
  const float* feat = (const float*)d_in[0];   // (2048, 2, 128) f32 -> (4096,128)
  const float* attn = (const float*)d_in[1];   // (4096, 4096) f32
  float* out = (float*)d_out;                  // [loss, masked_scores(16.7M)]
  float* msOut = out + 1;

  float* Zv       = (float*)d_ws;                       // NN
  float* numer    = Zv + NN;                            // NN
  int*   suppCnt  = (int*)(numer + NN);                 // NN
  int*   suppIdx  = suppCnt + NN;                       // NN*SUPP_CAP
  float* suppVal  = (float*)(suppIdx + (size_t)NN * SUPP_CAP);  // NN*SUPP_CAP
  unsigned short* fbf = (unsigned short*)(suppVal + (size_t)NN * SUPP_CAP);

  k_prep<<<dim3(1024), dim3(256), 0, stream>>>(feat, fbf, Zv);
  k_sparsemax<<<dim3(4096), dim3(256), 0, stream>>>(attn, msOut, suppCnt,
                                                    suppIdx, suppVal);
  k_gram<<<dim3(32, 32), dim3(256), 0, stream>>>(fbf, Zv);
  k_corr<<<dim3(1024), dim3(256), 0, stream>>>(fbf, suppCnt, suppIdx, suppVal,
                                               Zv, numer);
  k_loss<<<dim3(1), dim3(256), 0, stream>>>(Zv, numer, out);
}

// Round 5
// 160.232 us; speedup vs baseline: 1.1134x; 1.1134x over previous
//
#include <hip/hip_runtime.h>
#include <math.h>

#define NN   4096            // N = V*B
#define BD   2048            // B
#define DF   128             // D
#define INV_T (1.0f/0.07f)
#define SUPP_CAP 32          // max sparsemax support tracked per row (actual ~1-3)
#define CAND_CAP 128         // candidates z > max-1 (superset of support)

typedef __attribute__((ext_vector_type(8))) short short8v;   // 8 x bf16
typedef __attribute__((ext_vector_type(4))) float float4v;
typedef float f4a __attribute__((ext_vector_type(4), aligned(4)));  // 4B-aligned float4

__device__ inline unsigned short f2bf_rne(float x) {
  unsigned int u = __float_as_uint(x);
  u = (u + 0x7FFFu + ((u >> 16) & 1u)) >> 16;
  return (unsigned short)u;
}
__device__ inline float bf2f(unsigned short h) {
  return __uint_as_float(((unsigned int)h) << 16);
}

// ---------------- Kernel 1: normalize features -> bf16, zero Z ----------------
__global__ void k_prep(const float* __restrict__ feat,
                       unsigned short* __restrict__ fbf,
                       float* __restrict__ Zv) {
  int gid  = blockIdx.x * blockDim.x + threadIdx.x;
  int row  = gid >> 6;                                // one wave per row
  int lane = threadIdx.x & 63;
  const float2* src = (const float2*)(feat + (size_t)row * DF);
  float2 v = src[lane];
  float ss = v.x * v.x + v.y * v.y;
  #pragma unroll
  for (int off = 1; off < 64; off <<= 1) ss += __shfl_xor(ss, off, 64);
  float inv = rsqrtf(ss);
  ushort2 o;
  o.x = f2bf_rne(v.x * inv);
  o.y = f2bf_rne(v.y * inv);
  ((ushort2*)(fbf + (size_t)row * DF))[lane] = o;
  if (gid < NN) Zv[gid] = 0.f;
}

// ---------------- Kernel 2: sparsemax per row ----------------
// tau >= max-1, so support \subseteq {z > max-1} (typically 1-3 elements).
// Collect candidates to LDS, run exact monotone Newton serially on thread 0,
// then one vectorized ms-store pass. 3 barriers total.
__global__ __launch_bounds__(256) void k_sparsemax(
    const float* __restrict__ attn,
    float* __restrict__ msOut,   // d_out + 1
    int* __restrict__ suppCnt,
    int* __restrict__ suppIdx,
    float* __restrict__ suppVal) {
  __shared__ float redM[4];
  __shared__ float cand[CAND_CAP];
  __shared__ int ccnt;
  __shared__ float tauS;
  int row  = blockIdx.x;
  int tid  = threadIdx.x;
  int lane = tid & 63, wv = tid >> 6;
  const float4* arow = (const float4*)(attn + (size_t)row * NN);
  int rb = row & (BD - 1);
  float z[16];
  #pragma unroll
  for (int u = 0; u < 4; ++u) {
    int q = u * 256 + tid;            // float4 index: perfectly coalesced
    float4 a = arow[q];
    int j = q * 4;
    z[4*u+0] = (((j+0) & (BD-1)) == rb) ? 0.f : a.x * INV_T;
    z[4*u+1] = (((j+1) & (BD-1)) == rb) ? 0.f : a.y * INV_T;
    z[4*u+2] = (((j+2) & (BD-1)) == rb) ? 0.f : a.z * INV_T;
    z[4*u+3] = (((j+3) & (BD-1)) == rb) ? 0.f : a.w * INV_T;
  }
  // row max
  float m = z[0];
  #pragma unroll
  for (int u = 1; u < 16; ++u) m = fmaxf(m, z[u]);
  #pragma unroll
  for (int off = 1; off < 64; off <<= 1) m = fmaxf(m, __shfl_xor(m, off, 64));
  if (lane == 0) redM[wv] = m;
  if (tid == 0) ccnt = 0;
  __syncthreads();                                      // barrier 1
  m = fmaxf(fmaxf(redM[0], redM[1]), fmaxf(redM[2], redM[3]));

  // collect candidates z > m-1 (rare; divergence negligible)
  float thresh = m - 1.0f;
  #pragma unroll
  for (int u = 0; u < 16; ++u) {
    if (z[u] > thresh) {
      int slot = atomicAdd(&ccnt, 1);
      if (slot < CAND_CAP) cand[slot] = z[u];
    }
  }
  __syncthreads();                                      // barrier 2

  if (tid == 0) {
    int nc = min(ccnt, CAND_CAP);
    float tau = thresh;
    #pragma unroll 1
    for (int it = 0; it < 32; ++it) {
      float S = 0.f; float C = 0.f;
      for (int e = 0; e < nc; ++e) {
        float v = cand[e];
        if (v > tau) { S += v; C += 1.f; }
      }
      float nt = (C > 0.f) ? (S - 1.0f) / C : tau;
      if (nt == tau) break;
      tau = nt;
    }
    tauS = tau;
  }
  __syncthreads();                                      // barrier 3
  float tau = tauS;
  if (tid == 0) {
    // serial support emit (support size ~1-3)
    int sc = 0;
    int nc = min(ccnt, CAND_CAP);
    (void)nc;
    suppCnt[row] = 0;   // placeholder; rewritten below via atomic path
  }

  // store ms (vectorized, 4B-aligned dwordx4) and emit support entries
  float* orow = msOut + (size_t)row * NN;
  __shared__ int scnt;
  if (tid == 0) scnt = 0;
  __syncthreads();
  #pragma unroll
  for (int u = 0; u < 4; ++u) {
    int j = (u * 256 + tid) * 4;
    f4a v;
    v.x = fmaxf(z[4*u+0] - tau, 0.f);
    v.y = fmaxf(z[4*u+1] - tau, 0.f);
    v.z = fmaxf(z[4*u+2] - tau, 0.f);
    v.w = fmaxf(z[4*u+3] - tau, 0.f);
    *((f4a*)(orow + j)) = v;
    if (v.x > 0.f || v.y > 0.f || v.z > 0.f || v.w > 0.f) {
      float mv[4] = {v.x, v.y, v.z, v.w};
      #pragma unroll
      for (int t = 0; t < 4; ++t) {
        if (mv[t] > 0.f) {
          int slot = atomicAdd(&scnt, 1);
          if (slot < SUPP_CAP) {
            suppIdx[row * SUPP_CAP + slot] = j + t;
            suppVal[row * SUPP_CAP + slot] = mv[t];
          }
        }
      }
    }
  }
  __syncthreads();
  if (tid == 0) suppCnt[row] = min(scnt, SUPP_CAP);
}

// ---------------- Kernel 3: pure MFMA Gram + Z0 reduction + numer ----------------
// Z0_i = sum_{j != i} exp(sim_ij - 1/T); numer_i = sim(i,pos)-1/T grabbed when
// the tile covers the positive column. F (4096x128 bf16, 1 MB) is L2-resident
// -> no LDS. Block = 4 waves (2x2) -> 128x128 C-tile.
__global__ __launch_bounds__(256) void k_gram(
    const unsigned short* __restrict__ fbf, float* __restrict__ Zv,
    float* __restrict__ numer) {
  int tid = threadIdx.x;
  int wave = tid >> 6, lane = tid & 63;
  int c = lane & 15, quad = lane >> 4;
  int wi = wave >> 1, wj = wave & 1;
  int i0 = blockIdx.y * 128 + wi * 64;
  int j0 = blockIdx.x * 128 + wj * 64;

  const unsigned short* aBase = fbf + (size_t)(i0 + c) * DF + quad * 8;
  const unsigned short* bBase = fbf + (size_t)(j0 + c) * DF + quad * 8;

  float4v acc[4][4];
  #pragma unroll
  for (int m = 0; m < 4; ++m)
    #pragma unroll
    for (int n = 0; n < 4; ++n) acc[m][n] = (float4v){0.f, 0.f, 0.f, 0.f};

  #pragma unroll
  for (int k0 = 0; k0 < DF; k0 += 32) {
    short8v afr[4], bfr[4];
    #pragma unroll
    for (int m = 0; m < 4; ++m)
      afr[m] = *(const short8v*)(aBase + (size_t)(m * 16) * DF + k0);
    #pragma unroll
    for (int n = 0; n < 4; ++n)
      bfr[n] = *(const short8v*)(bBase + (size_t)(n * 16) * DF + k0);
    #pragma unroll
    for (int m = 0; m < 4; ++m)
      #pragma unroll
      for (int n = 0; n < 4; ++n)
        acc[m][n] = __builtin_amdgcn_mfma_f32_16x16x32_bf16(
            afr[m], bfr[n], acc[m][n], 0, 0, 0);
  }

  // epilogue (C/D: col=lane&15, row=quad*4+r)
  #pragma unroll
  for (int m = 0; m < 4; ++m) {
    #pragma unroll
    for (int r = 0; r < 4; ++r) {
      int i = i0 + m * 16 + quad * 4 + r;
      int pos = (i + BD) & (NN - 1);
      float zsum = 0.f;
      #pragma unroll
      for (int n = 0; n < 4; ++n) {
        int j = j0 + n * 16 + c;
        float simv = acc[m][n][r] * INV_T - INV_T;
        float e = __expf(simv);
        zsum += (i == j) ? 0.f : e;
        if (j == pos) numer[i] = simv;
      }
      zsum += __shfl_xor(zsum, 1, 64);
      zsum += __shfl_xor(zsum, 2, 64);
      zsum += __shfl_xor(zsum, 4, 64);
      zsum += __shfl_xor(zsum, 8, 64);
      if (c == 0) atomicAdd(&Zv[i], zsum);
    }
  }
}

// ---------------- Kernel 3b: sparse support correction ----------------
// One wave per row: Z_i -= sum_{e in supp(i)} exp(sim(i,j_e) - 1/T) * ms_e.
__global__ __launch_bounds__(256) void k_corr(
    const unsigned short* __restrict__ fbf,
    const int* __restrict__ suppCnt, const int* __restrict__ suppIdx,
    const float* __restrict__ suppVal, float* __restrict__ Zv) {
  int tid = threadIdx.x;
  int wave = tid >> 6, lane = tid & 63;
  int row = blockIdx.x * 4 + wave;
  int cnt = suppCnt[row];
  if (cnt == 0) return;
  ushort2 a = ((const ushort2*)(fbf + (size_t)row * DF))[lane];
  float ax = bf2f(a.x), ay = bf2f(a.y);
  float corr = 0.f;
  for (int e = 0; e < cnt; ++e) {
    int j = suppIdx[row * SUPP_CAP + e];
    float v = suppVal[row * SUPP_CAP + e];
    ushort2 g = ((const ushort2*)(fbf + (size_t)j * DF))[lane];
    float s = ax * bf2f(g.x) + ay * bf2f(g.y);
    #pragma unroll
    for (int off = 1; off < 64; off <<= 1) s += __shfl_xor(s, off, 64);
    corr += __expf(s * INV_T - INV_T) * v;
  }
  if (lane == 0) atomicAdd(&Zv[row], -corr);
}

// ---------------- Kernel 4: finalize loss (single block) ----------------
__global__ void k_loss(const float* __restrict__ Zv,
                       const float* __restrict__ numer,
                       float* __restrict__ out) {
  float acc = 0.f;
  for (int i = threadIdx.x; i < NN; i += 256)
    acc += numer[i] - logf(Zv[i]);
  #pragma unroll
  for (int off = 1; off < 64; off <<= 1) acc += __shfl_xor(acc, off, 64);
  __shared__ float red[4];
  int wv = threadIdx.x >> 6, lane = threadIdx.x & 63;
  if (lane == 0) red[wv] = acc;
  __syncthreads();
  if (threadIdx.x == 0) {
    float t = (red[0] + red[1]) + (red[2] + red[3]);
    out[0] = -t / (float)NN;
  }
}

extern "C" void kernel_launch(void* const* d_in, const int* in_sizes, int n_in,
                              void* d_out, int out_size, void* d_ws, size_t ws_size,
                              hipStream_t stream) {
  const float* feat = (const float*)d_in[0];   // (2048, 2, 128) f32 -> (4096,128)
  const float* attn = (const float*)d_in[1];   // (4096, 4096) f32
  float* out = (float*)d_out;                  // [loss, masked_scores(16.7M)]
  float* msOut = out + 1;

  float* Zv       = (float*)d_ws;                       // NN
  float* numer    = Zv + NN;                            // NN
  int*   suppCnt  = (int*)(numer + NN);                 // NN
  int*   suppIdx  = suppCnt + NN;                       // NN*SUPP_CAP
  float* suppVal  = (float*)(suppIdx + (size_t)NN * SUPP_CAP);  // NN*SUPP_CAP
  unsigned short* fbf = (unsigned short*)(suppVal + (size_t)NN * SUPP_CAP);

  k_prep<<<dim3(1024), dim3(256), 0, stream>>>(feat, fbf, Zv);
  k_sparsemax<<<dim3(4096), dim3(256), 0, stream>>>(attn, msOut, suppCnt,
                                                    suppIdx, suppVal);
  k_gram<<<dim3(32, 32), dim3(256), 0, stream>>>(fbf, Zv, numer);
  k_corr<<<dim3(1024), dim3(256), 0, stream>>>(fbf, suppCnt, suppIdx, suppVal, Zv);
  k_loss<<<dim3(1), dim3(256), 0, stream>>>(Zv, numer, out);
}

// Round 6
// 149.180 us; speedup vs baseline: 1.1959x; 1.0741x over previous
//
#include <hip/hip_runtime.h>
#include <math.h>

#define NN   4096            // N = V*B
#define BD   2048            // B
#define DF   128             // D
#define INV_T (1.0f/0.07f)
#define CAND_CAP 128         // candidates z > max-1 (superset of support, actual ~1-3)

typedef __attribute__((ext_vector_type(8))) short short8v;   // 8 x bf16
typedef __attribute__((ext_vector_type(4))) float float4v;
typedef float f4a __attribute__((ext_vector_type(4), aligned(4)));  // 4B-aligned float4

__device__ inline unsigned short f2bf_rne(float x) {
  unsigned int u = __float_as_uint(x);
  u = (u + 0x7FFFu + ((u >> 16) & 1u)) >> 16;
  return (unsigned short)u;
}
__device__ inline float bf2f(unsigned short h) {
  return __uint_as_float(((unsigned int)h) << 16);
}

// ---------------- Kernel 1: normalize features -> bf16, zero Z ----------------
__global__ void k_prep(const float* __restrict__ feat,
                       unsigned short* __restrict__ fbf,
                       float* __restrict__ Zv) {
  int gid  = blockIdx.x * blockDim.x + threadIdx.x;
  int row  = gid >> 6;                                // one wave per row
  int lane = threadIdx.x & 63;
  const float2* src = (const float2*)(feat + (size_t)row * DF);
  float2 v = src[lane];
  float ss = v.x * v.x + v.y * v.y;
  #pragma unroll
  for (int off = 1; off < 64; off <<= 1) ss += __shfl_xor(ss, off, 64);
  float inv = rsqrtf(ss);
  ushort2 o;
  o.x = f2bf_rne(v.x * inv);
  o.y = f2bf_rne(v.y * inv);
  ((ushort2*)(fbf + (size_t)row * DF))[lane] = o;
  if (gid < NN) Zv[gid] = 0.f;
}

// ---------------- Kernel 2: sparsemax + fused sparse Z-correction ----------------
// tau >= max-1, so support \subseteq candidates {z > max-1} (typically 1-3).
// Candidates (value + index) go to LDS; thread 0 runs exact monotone Newton
// (tau' = (sum_{z>tau} z - 1)/|{z>tau}|, finitely convergent). Store pass is
// branch-free dwordx4. Correction Z_row -= sum_supp exp(sim(row,j)-1/T)*ms_j
// is applied here directly (atomicAdd order-independent; Zv zeroed in k_prep).
__global__ __launch_bounds__(256) void k_sparsemax(
    const float* __restrict__ attn,
    const unsigned short* __restrict__ fbf,
    float* __restrict__ msOut,   // d_out + 1
    float* __restrict__ Zv) {
  __shared__ float redM[4];
  __shared__ float cand[CAND_CAP];
  __shared__ int   cidx[CAND_CAP];
  __shared__ int ccnt;
  __shared__ float tauS;
  __shared__ float corrS[4];
  int row  = blockIdx.x;
  int tid  = threadIdx.x;
  int lane = tid & 63, wv = tid >> 6;
  const float4* arow = (const float4*)(attn + (size_t)row * NN);
  int rb = row & (BD - 1);
  float z[16];
  #pragma unroll
  for (int u = 0; u < 4; ++u) {
    int q = u * 256 + tid;            // float4 index: perfectly coalesced
    float4 a = arow[q];
    int j = q * 4;
    z[4*u+0] = (((j+0) & (BD-1)) == rb) ? 0.f : a.x * INV_T;
    z[4*u+1] = (((j+1) & (BD-1)) == rb) ? 0.f : a.y * INV_T;
    z[4*u+2] = (((j+2) & (BD-1)) == rb) ? 0.f : a.z * INV_T;
    z[4*u+3] = (((j+3) & (BD-1)) == rb) ? 0.f : a.w * INV_T;
  }
  // row max
  float m = z[0];
  #pragma unroll
  for (int u = 1; u < 16; ++u) m = fmaxf(m, z[u]);
  #pragma unroll
  for (int off = 1; off < 64; off <<= 1) m = fmaxf(m, __shfl_xor(m, off, 64));
  if (lane == 0) redM[wv] = m;
  if (tid == 0) ccnt = 0;
  __syncthreads();                                      // barrier 1
  m = fmaxf(fmaxf(redM[0], redM[1]), fmaxf(redM[2], redM[3]));

  // collect candidates z > m-1 (rare; divergence negligible)
  float thresh = m - 1.0f;
  #pragma unroll
  for (int u = 0; u < 4; ++u) {
    #pragma unroll
    for (int t = 0; t < 4; ++t) {
      if (z[4*u+t] > thresh) {
        int slot = atomicAdd(&ccnt, 1);
        if (slot < CAND_CAP) {
          cand[slot] = z[4*u+t];
          cidx[slot] = (u * 256 + tid) * 4 + t;
        }
      }
    }
  }
  __syncthreads();                                      // barrier 2

  if (tid == 0) {
    int nc = min(ccnt, CAND_CAP);
    float tau = thresh;
    #pragma unroll 1
    for (int it = 0; it < 32; ++it) {
      float S = 0.f; float C = 0.f;
      for (int e = 0; e < nc; ++e) {
        float v = cand[e];
        if (v > tau) { S += v; C += 1.f; }
      }
      float nt = (C > 0.f) ? (S - 1.0f) / C : tau;
      if (nt == tau) break;
      tau = nt;
    }
    tauS = tau;
  }
  __syncthreads();                                      // barrier 3
  float tau = tauS;

  // branch-free vectorized ms store (4B-aligned dwordx4; d_out+1 base)
  float* orow = msOut + (size_t)row * NN;
  #pragma unroll
  for (int u = 0; u < 4; ++u) {
    int j = (u * 256 + tid) * 4;
    f4a v;
    v.x = fmaxf(z[4*u+0] - tau, 0.f);
    v.y = fmaxf(z[4*u+1] - tau, 0.f);
    v.z = fmaxf(z[4*u+2] - tau, 0.f);
    v.w = fmaxf(z[4*u+3] - tau, 0.f);
    *((f4a*)(orow + j)) = v;
  }

  // fused correction: waves split candidate entries; dot over 128 bf16 dims
  int nc = min(ccnt, CAND_CAP);
  ushort2 fr = ((const ushort2*)(fbf + (size_t)row * DF))[lane];
  float fx = bf2f(fr.x), fy = bf2f(fr.y);
  float corr = 0.f;
  for (int e = wv; e < nc; e += 4) {
    float msv = cand[e] - tau;
    if (msv <= 0.f) continue;
    int j = cidx[e];
    ushort2 g = ((const ushort2*)(fbf + (size_t)j * DF))[lane];
    float s = fx * bf2f(g.x) + fy * bf2f(g.y);
    #pragma unroll
    for (int off = 1; off < 64; off <<= 1) s += __shfl_xor(s, off, 64);
    corr += __expf(s * INV_T - INV_T) * msv;
  }
  if (lane == 0) corrS[wv] = corr;
  __syncthreads();                                      // barrier 4
  if (tid == 0) {
    float tot = (corrS[0] + corrS[1]) + (corrS[2] + corrS[3]);
    if (tot != 0.f) atomicAdd(&Zv[row], -tot);
  }
}

// ---------------- Kernel 3: symmetric MFMA Gram + Z0 + numer ----------------
// Upper-triangle 128x128 tiles only (528 blocks). Each element (i<j) credits
// exp(sim-1/T) to Z_i (row-reduce over c-lanes) and Z_j (col-reduce over
// quads via shfl 16/32). numer written for both ends of the positive pair.
__global__ __launch_bounds__(256) void k_gram(
    const unsigned short* __restrict__ fbf, float* __restrict__ Zv,
    float* __restrict__ numer) {
  // decode linear block id -> upper-tri tile (bi <= bj), 32 block-rows
  int t = blockIdx.x, bi = 0, L = 32;
  while (t >= L) { t -= L; --L; ++bi; }
  int bj = bi + t;

  int tid = threadIdx.x;
  int wave = tid >> 6, lane = tid & 63;
  int c = lane & 15, quad = lane >> 4;
  int wi = wave >> 1, wj = wave & 1;
  if (bi == bj && wi > wj) return;      // fully-below-diagonal wave: no work
  int i0 = bi * 128 + wi * 64;
  int j0 = bj * 128 + wj * 64;

  const unsigned short* aBase = fbf + (size_t)(i0 + c) * DF + quad * 8;
  const unsigned short* bBase = fbf + (size_t)(j0 + c) * DF + quad * 8;

  float4v acc[4][4];
  #pragma unroll
  for (int m = 0; m < 4; ++m)
    #pragma unroll
    for (int n = 0; n < 4; ++n) acc[m][n] = (float4v){0.f, 0.f, 0.f, 0.f};

  #pragma unroll
  for (int k0 = 0; k0 < DF; k0 += 32) {
    short8v afr[4], bfr[4];
    #pragma unroll
    for (int m = 0; m < 4; ++m)
      afr[m] = *(const short8v*)(aBase + (size_t)(m * 16) * DF + k0);
    #pragma unroll
    for (int n = 0; n < 4; ++n)
      bfr[n] = *(const short8v*)(bBase + (size_t)(n * 16) * DF + k0);
    #pragma unroll
    for (int m = 0; m < 4; ++m)
      #pragma unroll
      for (int n = 0; n < 4; ++n)
        acc[m][n] = __builtin_amdgcn_mfma_f32_16x16x32_bf16(
            afr[m], bfr[n], acc[m][n], 0, 0, 0);
  }

  // epilogue (C/D: col=lane&15, row=quad*4+r); count each unordered pair once
  float colacc[4] = {0.f, 0.f, 0.f, 0.f};
  #pragma unroll
  for (int m = 0; m < 4; ++m) {
    #pragma unroll
    for (int r = 0; r < 4; ++r) {
      int i = i0 + m * 16 + quad * 4 + r;
      float zrow = 0.f;
      #pragma unroll
      for (int n = 0; n < 4; ++n) {
        int j = j0 + n * 16 + c;
        float simv = acc[m][n][r] * INV_T - INV_T;
        float e = (j > i) ? __expf(simv) : 0.f;
        zrow += e;
        colacc[n] += e;
        if (j - i == BD) { numer[i] = simv; numer[j] = simv; }
      }
      zrow += __shfl_xor(zrow, 1, 64);
      zrow += __shfl_xor(zrow, 2, 64);
      zrow += __shfl_xor(zrow, 4, 64);
      zrow += __shfl_xor(zrow, 8, 64);
      if (c == 0) atomicAdd(&Zv[i], zrow);
    }
  }
  #pragma unroll
  for (int n = 0; n < 4; ++n) {
    float v = colacc[n];
    v += __shfl_xor(v, 16, 64);
    v += __shfl_xor(v, 32, 64);
    if (quad == 0) atomicAdd(&Zv[j0 + n * 16 + c], v);
  }
}

// ---------------- Kernel 4: finalize loss (single block) ----------------
__global__ void k_loss(const float* __restrict__ Zv,
                       const float* __restrict__ numer,
                       float* __restrict__ out) {
  float acc = 0.f;
  for (int i = threadIdx.x; i < NN; i += 256)
    acc += numer[i] - logf(Zv[i]);
  #pragma unroll
  for (int off = 1; off < 64; off <<= 1) acc += __shfl_xor(acc, off, 64);
  __shared__ float red[4];
  int wv = threadIdx.x >> 6, lane = threadIdx.x & 63;
  if (lane == 0) red[wv] = acc;
  __syncthreads();
  if (threadIdx.x == 0) {
    float t = (red[0] + red[1]) + (red[2] + red[3]);
    out[0] = -t / (float)NN;
  }
}

extern "C" void kernel_launch(void* const* d_in, const int* in_sizes, int n_in,
                              void* d_out, int out_size, void* d_ws, size_t ws_size,
                              hipStream_t stream) {
  const float* feat = (const float*)d_in[0];   // (2048, 2, 128) f32 -> (4096,128)
  const float* attn = (const float*)d_in[1];   // (4096, 4096) f32
  float* out = (float*)d_out;                  // [loss, masked_scores(16.7M)]
  float* msOut = out + 1;

  float* Zv    = (float*)d_ws;                 // NN
  float* numer = Zv + NN;                      // NN
  unsigned short* fbf = (unsigned short*)(numer + NN);  // NN*DF bf16

  k_prep<<<dim3(1024), dim3(256), 0, stream>>>(feat, fbf, Zv);
  k_sparsemax<<<dim3(4096), dim3(256), 0, stream>>>(attn, fbf, msOut, Zv);
  k_gram<<<dim3(528), dim3(256), 0, stream>>>(fbf, Zv, numer);
  k_loss<<<dim3(1), dim3(256), 0, stream>>>(Zv, numer, out);
}

// Round 7
// 148.522 us; speedup vs baseline: 1.2012x; 1.0044x over previous
//
#include <hip/hip_runtime.h>
#include <math.h>

#define NN   4096            // N = V*B
#define BD   2048            // B
#define DF   128             // D
#define INV_T (1.0f/0.07f)
#define CAND_CAP 128         // candidates z > max-1 (superset of support, actual ~1-3)

typedef __attribute__((ext_vector_type(8))) short short8v;   // 8 x bf16
typedef __attribute__((ext_vector_type(4))) float float4v;
typedef float f4a __attribute__((ext_vector_type(4), aligned(4)));  // 4B-aligned float4

__device__ inline unsigned short f2bf_rne(float x) {
  unsigned int u = __float_as_uint(x);
  u = (u + 0x7FFFu + ((u >> 16) & 1u)) >> 16;
  return (unsigned short)u;
}

// ---------------- Kernel 1: sparsemax + fused prep + sparse Z-correction -----
// One block per row.
//  * wave 0 normalizes feat[row]: bf16 -> fbf (for k_gram), fp32 -> LDS (corr)
//  * tau via exact monotone Newton on the candidate set {z > max-1} (support
//    superset, ~1-3 elems); finitely convergent (== support-set refinement)
//  * branch-free dwordx4 ms store to d_out+1
//  * Zv[row] = -sum_supp exp(sim-1/T)*ms  (plain store; k_gram atomicAdds Z0
//    on top; corr sim from fp32 feats — mismatch vs bf16 gram sim is ~1e-7
//    absolute in Z ~ 3e-3, negligible)
__global__ __launch_bounds__(256) void k_sparsemax(
    const float* __restrict__ attn,
    const float* __restrict__ feat,
    unsigned short* __restrict__ fbf,
    float* __restrict__ msOut,   // d_out + 1
    float* __restrict__ Zv) {
  __shared__ float redM[4];
  __shared__ float cand[CAND_CAP];
  __shared__ int   cidx[CAND_CAP];
  __shared__ int ccnt;
  __shared__ float tauS;
  __shared__ float corrS[4];
  __shared__ float2 fN[64];          // normalized fp32 feature row (128 floats)
  int row  = blockIdx.x;
  int tid  = threadIdx.x;
  int lane = tid & 63, wv = tid >> 6;

  // ---- fused prep (wave 0 only) ----
  if (wv == 0) {
    float2 v = ((const float2*)(feat + (size_t)row * DF))[lane];
    float ss = v.x * v.x + v.y * v.y;
    #pragma unroll
    for (int off = 1; off < 64; off <<= 1) ss += __shfl_xor(ss, off, 64);
    float inv = rsqrtf(ss);
    float2 nv; nv.x = v.x * inv; nv.y = v.y * inv;
    ushort2 o; o.x = f2bf_rne(nv.x); o.y = f2bf_rne(nv.y);
    ((ushort2*)(fbf + (size_t)row * DF))[lane] = o;
    fN[lane] = nv;
  }

  const float4* arow = (const float4*)(attn + (size_t)row * NN);
  int rb = row & (BD - 1);
  float z[16];
  #pragma unroll
  for (int u = 0; u < 4; ++u) {
    int q = u * 256 + tid;            // float4 index: perfectly coalesced
    float4 a = arow[q];
    int j = q * 4;
    z[4*u+0] = (((j+0) & (BD-1)) == rb) ? 0.f : a.x * INV_T;
    z[4*u+1] = (((j+1) & (BD-1)) == rb) ? 0.f : a.y * INV_T;
    z[4*u+2] = (((j+2) & (BD-1)) == rb) ? 0.f : a.z * INV_T;
    z[4*u+3] = (((j+3) & (BD-1)) == rb) ? 0.f : a.w * INV_T;
  }
  // row max
  float m = z[0];
  #pragma unroll
  for (int u = 1; u < 16; ++u) m = fmaxf(m, z[u]);
  #pragma unroll
  for (int off = 1; off < 64; off <<= 1) m = fmaxf(m, __shfl_xor(m, off, 64));
  if (lane == 0) redM[wv] = m;
  if (tid == 0) ccnt = 0;
  __syncthreads();                                      // barrier 1
  m = fmaxf(fmaxf(redM[0], redM[1]), fmaxf(redM[2], redM[3]));

  // collect candidates z > m-1 (rare; divergence negligible)
  float thresh = m - 1.0f;
  #pragma unroll
  for (int u = 0; u < 4; ++u) {
    #pragma unroll
    for (int t = 0; t < 4; ++t) {
      if (z[4*u+t] > thresh) {
        int slot = atomicAdd(&ccnt, 1);
        if (slot < CAND_CAP) {
          cand[slot] = z[4*u+t];
          cidx[slot] = (u * 256 + tid) * 4 + t;
        }
      }
    }
  }
  __syncthreads();                                      // barrier 2

  if (tid == 0) {
    int nc = min(ccnt, CAND_CAP);
    float tau = thresh;
    #pragma unroll 1
    for (int it = 0; it < 32; ++it) {
      float S = 0.f; float C = 0.f;
      for (int e = 0; e < nc; ++e) {
        float v = cand[e];
        if (v > tau) { S += v; C += 1.f; }
      }
      float nt = (C > 0.f) ? (S - 1.0f) / C : tau;
      if (nt == tau) break;
      tau = nt;
    }
    tauS = tau;
  }
  __syncthreads();                                      // barrier 3
  float tau = tauS;

  // branch-free vectorized ms store (4B-aligned dwordx4; d_out+1 base)
  float* orow = msOut + (size_t)row * NN;
  #pragma unroll
  for (int u = 0; u < 4; ++u) {
    int j = (u * 256 + tid) * 4;
    f4a v;
    v.x = fmaxf(z[4*u+0] - tau, 0.f);
    v.y = fmaxf(z[4*u+1] - tau, 0.f);
    v.z = fmaxf(z[4*u+2] - tau, 0.f);
    v.w = fmaxf(z[4*u+3] - tau, 0.f);
    *((f4a*)(orow + j)) = v;
  }

  // fused correction: waves split support entries; fp32 dot over 128 dims
  int nc = min(ccnt, CAND_CAP);
  float2 fi = fN[lane];
  float corr = 0.f;
  for (int e = wv; e < nc; e += 4) {
    float msv = cand[e] - tau;
    if (msv <= 0.f) continue;
    int j = cidx[e];
    float2 g = ((const float2*)(feat + (size_t)j * DF))[lane];
    float dt = fi.x * g.x + fi.y * g.y;
    float sj = g.x * g.x + g.y * g.y;
    #pragma unroll
    for (int off = 1; off < 64; off <<= 1) {
      dt += __shfl_xor(dt, off, 64);
      sj += __shfl_xor(sj, off, 64);
    }
    float s = dt * rsqrtf(sj);
    corr += __expf(s * INV_T - INV_T) * msv;
  }
  if (lane == 0) corrS[wv] = corr;
  __syncthreads();                                      // barrier 4
  if (tid == 0) {
    float tot = (corrS[0] + corrS[1]) + (corrS[2] + corrS[3]);
    Zv[row] = -tot;                  // plain store: initializes Z for k_gram
  }
}

// ---------------- Kernel 2: symmetric MFMA Gram + Z0 + numer ----------------
// Upper-triangle 128x128 tiles only (528 blocks). Each element (i<j) credits
// exp(sim-1/T) to Z_i (row-reduce over c-lanes) and Z_j (col-reduce over
// quads via shfl 16/32). numer written for both ends of the positive pair.
__global__ __launch_bounds__(256) void k_gram(
    const unsigned short* __restrict__ fbf, float* __restrict__ Zv,
    float* __restrict__ numer) {
  // decode linear block id -> upper-tri tile (bi <= bj), 32 block-rows
  int t = blockIdx.x, bi = 0, L = 32;
  while (t >= L) { t -= L; --L; ++bi; }
  int bj = bi + t;

  int tid = threadIdx.x;
  int wave = tid >> 6, lane = tid & 63;
  int c = lane & 15, quad = lane >> 4;
  int wi = wave >> 1, wj = wave & 1;
  if (bi == bj && wi > wj) return;      // fully-below-diagonal wave: no work
  int i0 = bi * 128 + wi * 64;
  int j0 = bj * 128 + wj * 64;

  const unsigned short* aBase = fbf + (size_t)(i0 + c) * DF + quad * 8;
  const unsigned short* bBase = fbf + (size_t)(j0 + c) * DF + quad * 8;

  float4v acc[4][4];
  #pragma unroll
  for (int m = 0; m < 4; ++m)
    #pragma unroll
    for (int n = 0; n < 4; ++n) acc[m][n] = (float4v){0.f, 0.f, 0.f, 0.f};

  #pragma unroll
  for (int k0 = 0; k0 < DF; k0 += 32) {
    short8v afr[4], bfr[4];
    #pragma unroll
    for (int m = 0; m < 4; ++m)
      afr[m] = *(const short8v*)(aBase + (size_t)(m * 16) * DF + k0);
    #pragma unroll
    for (int n = 0; n < 4; ++n)
      bfr[n] = *(const short8v*)(bBase + (size_t)(n * 16) * DF + k0);
    #pragma unroll
    for (int m = 0; m < 4; ++m)
      #pragma unroll
      for (int n = 0; n < 4; ++n)
        acc[m][n] = __builtin_amdgcn_mfma_f32_16x16x32_bf16(
            afr[m], bfr[n], acc[m][n], 0, 0, 0);
  }

  // epilogue (C/D: col=lane&15, row=quad*4+r); count each unordered pair once
  float colacc[4] = {0.f, 0.f, 0.f, 0.f};
  #pragma unroll
  for (int m = 0; m < 4; ++m) {
    #pragma unroll
    for (int r = 0; r < 4; ++r) {
      int i = i0 + m * 16 + quad * 4 + r;
      float zrow = 0.f;
      #pragma unroll
      for (int n = 0; n < 4; ++n) {
        int j = j0 + n * 16 + c;
        float simv = acc[m][n][r] * INV_T - INV_T;
        float e = (j > i) ? __expf(simv) : 0.f;
        zrow += e;
        colacc[n] += e;
        if (j - i == BD) { numer[i] = simv; numer[j] = simv; }
      }
      zrow += __shfl_xor(zrow, 1, 64);
      zrow += __shfl_xor(zrow, 2, 64);
      zrow += __shfl_xor(zrow, 4, 64);
      zrow += __shfl_xor(zrow, 8, 64);
      if (c == 0) atomicAdd(&Zv[i], zrow);
    }
  }
  #pragma unroll
  for (int n = 0; n < 4; ++n) {
    float v = colacc[n];
    v += __shfl_xor(v, 16, 64);
    v += __shfl_xor(v, 32, 64);
    if (quad == 0) atomicAdd(&Zv[j0 + n * 16 + c], v);
  }
}

// ---------------- Kernel 3: finalize loss (single block) ----------------
__global__ void k_loss(const float* __restrict__ Zv,
                       const float* __restrict__ numer,
                       float* __restrict__ out) {
  float acc = 0.f;
  for (int i = threadIdx.x; i < NN; i += 256)
    acc += numer[i] - logf(Zv[i]);
  #pragma unroll
  for (int off = 1; off < 64; off <<= 1) acc += __shfl_xor(acc, off, 64);
  __shared__ float red[4];
  int wv = threadIdx.x >> 6, lane = threadIdx.x & 63;
  if (lane == 0) red[wv] = acc;
  __syncthreads();
  if (threadIdx.x == 0) {
    float t = (red[0] + red[1]) + (red[2] + red[3]);
    out[0] = -t / (float)NN;
  }
}

extern "C" void kernel_launch(void* const* d_in, const int* in_sizes, int n_in,
                              void* d_out, int out_size, void* d_ws, size_t ws_size,
                              hipStream_t stream) {
  const float* feat = (const float*)d_in[0];   // (2048, 2, 128) f32 -> (4096,128)
  const float* attn = (const float*)d_in[1];   // (4096, 4096) f32
  float* out = (float*)d_out;                  // [loss, masked_scores(16.7M)]
  float* msOut = out + 1;

  float* Zv    = (float*)d_ws;                 // NN
  float* numer = Zv + NN;                      // NN
  unsigned short* fbf = (unsigned short*)(numer + NN);  // NN*DF bf16

  k_sparsemax<<<dim3(4096), dim3(256), 0, stream>>>(attn, feat, fbf, msOut, Zv);
  k_gram<<<dim3(528), dim3(256), 0, stream>>>(fbf, Zv, numer);
  k_loss<<<dim3(1), dim3(256), 0, stream>>>(Zv, numer, out);
}